// Round 3
// baseline (336.232 us; speedup 1.0000x reference)
//
#include <hip/hip_runtime.h>
#include <math.h>

#define BB 2
#define LL 2048
#define DD 512
#define HH 8
#define DK 64
#define SK 40   // sample_k
#define UU 40   // top-k u
#define BH (BB*HH)   // 16
#define KT 1536      // split-bf16 packed K = 3*512

typedef __attribute__((ext_vector_type(8))) __bf16 bf16x8;
typedef __attribute__((ext_vector_type(4))) float f32x4;

__device__ inline ushort f2bf_rn(float f) {
    unsigned u = __float_as_uint(f);
    unsigned r = (u + 0x7fffu + ((u >> 16) & 1u)) >> 16;
    return (ushort)r;
}
__device__ inline float bf2f(ushort h) { return __uint_as_float(((unsigned)h) << 16); }

// ---------------- fill attns with 1/L ----------------
__global__ __launch_bounds__(256) void fill_attns(float* __restrict__ attns, long n4) {
    const float c = 1.0f / (float)LL;
    const float4 val = make_float4(c, c, c, c);
    float4* p = (float4*)attns;
    long stride = (long)gridDim.x * blockDim.x;
    for (long i = (long)blockIdx.x * blockDim.x + threadIdx.x; i < n4; i += stride)
        p[i] = val;
}

// ---------------- pack x -> A2[4096][1536] = [xh | xh | xl] ----------------
__global__ __launch_bounds__(256) void pack_x(const float* __restrict__ x, ushort* __restrict__ A2) {
    const int g = blockIdx.x * 256 + threadIdx.x;    // 0..262143
    const int r = g >> 6;                            // row 0..4095
    const int c = (g & 63) * 8;
    const float4 f0 = *(const float4*)&x[(long)r * DD + c];
    const float4 f1 = *(const float4*)&x[(long)r * DD + c + 4];
    float f[8] = {f0.x, f0.y, f0.z, f0.w, f1.x, f1.y, f1.z, f1.w};
    union { ushort s[8]; uint4 u; } H, L;
    #pragma unroll
    for (int i = 0; i < 8; ++i) {
        H.s[i] = f2bf_rn(f[i]);
        L.s[i] = f2bf_rn(f[i] - bf2f(H.s[i]));
    }
    ushort* rowp = A2 + (long)r * KT;
    *(uint4*)(rowp + c)        = H.u;
    *(uint4*)(rowp + 512 + c)  = H.u;
    *(uint4*)(rowp + 1024 + c) = L.u;
}

// ---------------- pack W -> B2[p][512][1536] = [Wh | Wl | Wh] ----------------
__global__ __launch_bounds__(256) void pack_w(
    const float* __restrict__ Wq, const float* __restrict__ Wk, const float* __restrict__ Wv,
    ushort* __restrict__ B2) {
    const int p = blockIdx.x >> 7;                   // 128 blocks per proj
    const float* W = (p == 0) ? Wq : ((p == 1) ? Wk : Wv);
    const int rem = (blockIdx.x & 127) * 256 + threadIdx.x;  // 0..32767
    const int r = rem >> 6;
    const int c = (rem & 63) * 8;
    const float4 f0 = *(const float4*)&W[(long)r * DD + c];
    const float4 f1 = *(const float4*)&W[(long)r * DD + c + 4];
    float f[8] = {f0.x, f0.y, f0.z, f0.w, f1.x, f1.y, f1.z, f1.w};
    union { ushort s[8]; uint4 u; } H, L;
    #pragma unroll
    for (int i = 0; i < 8; ++i) {
        H.s[i] = f2bf_rn(f[i]);
        L.s[i] = f2bf_rn(f[i] - bf2f(H.s[i]));
    }
    ushort* rowp = B2 + ((long)p * DD + r) * KT;
    *(uint4*)(rowp + c)        = H.u;   // Wh
    *(uint4*)(rowp + 512 + c)  = L.u;   // Wl
    *(uint4*)(rowp + 1024 + c) = H.u;   // Wh
}

// ---------------- MFMA projection GEMM: C = A2 @ B2^T + bias, out in [b][h][l][d] ----------------
// tile 128(M) x 64(N), BK=64, 4 waves each owning 64x32; K=1536
__global__ __launch_bounds__(256) void mfma_proj(
    const ushort* __restrict__ A2, const ushort* __restrict__ B2,
    const float* __restrict__ bq, const float* __restrict__ bk_, const float* __restrict__ bv,
    float* __restrict__ q, float* __restrict__ k, float* __restrict__ v)
{
    const int p = blockIdx.z;
    const float* bias = (p == 0) ? bq : ((p == 1) ? bk_ : bv);
    float* out = (p == 0) ? q : ((p == 1) ? k : v);
    const ushort* B = B2 + (long)p * DD * KT;

    __shared__ __attribute__((aligned(16))) ushort As[128 * 64];
    __shared__ __attribute__((aligned(16))) ushort Bs[64 * 64];

    const int tid = threadIdx.x;
    const int lane = tid & 63, w = tid >> 6;
    const int wr = w >> 1, wc = w & 1;
    const int m0 = blockIdx.x * 128, n0 = blockIdx.y * 64;

    // staging mapping: chunk c covers rows c*32 + (tid>>3), 8 bf16 at kk=(tid&7)*8
    const int t8 = tid >> 3;
    const int kk = (tid & 7) * 8;

    // fragment addressing
    const int arow = wr * 64 + (lane & 15);          // + i*16
    const int brow = wc * 32 + (lane & 15);          // + j*16
    const int kbase = (lane >> 4) * 16;              // byte offset of k-block within 32-k half
    const int aswz = (lane & 7) << 4;                // (row&7)<<4 — same for all frags (rows mod 8 = lane&7)

    f32x4 acc[4][2] = {};

    for (int k0 = 0; k0 < KT; k0 += 64) {
        // issue coalesced global loads for A (4 chunks) and B (2 chunks)
        uint4 ast[4], bst[2];
        #pragma unroll
        for (int c = 0; c < 4; ++c) {
            int row = c * 32 + t8;
            ast[c] = *(const uint4*)(A2 + (long)(m0 + row) * KT + k0 + kk);
        }
        #pragma unroll
        for (int c = 0; c < 2; ++c) {
            int row = c * 32 + t8;
            bst[c] = *(const uint4*)(B + (long)(n0 + row) * KT + k0 + kk);
        }
        __syncthreads();   // previous iteration's reads complete
        #pragma unroll
        for (int c = 0; c < 4; ++c) {
            int row = c * 32 + t8;
            int dst = row * 128 + ((kk * 2) ^ ((row & 7) << 4));
            *(uint4*)((char*)As + dst) = ast[c];
        }
        #pragma unroll
        for (int c = 0; c < 2; ++c) {
            int row = c * 32 + t8;
            int dst = row * 128 + ((kk * 2) ^ ((row & 7) << 4));
            *(uint4*)((char*)Bs + dst) = bst[c];
        }
        __syncthreads();
        #pragma unroll
        for (int ks = 0; ks < 2; ++ks) {
            const int kb = (ks * 64 + kbase) ^ aswz;
            uint4 b0 = *(const uint4*)((const char*)Bs + brow * 128 + kb);
            uint4 b1 = *(const uint4*)((const char*)Bs + (brow + 16) * 128 + kb);
            bf16x8 bf0 = __builtin_bit_cast(bf16x8, b0);
            bf16x8 bf1 = __builtin_bit_cast(bf16x8, b1);
            #pragma unroll
            for (int i = 0; i < 4; ++i) {
                uint4 av = *(const uint4*)((const char*)As + (arow + i * 16) * 128 + kb);
                bf16x8 af = __builtin_bit_cast(bf16x8, av);
                acc[i][0] = __builtin_amdgcn_mfma_f32_16x16x32_bf16(af, bf0, acc[i][0], 0, 0, 0);
                acc[i][1] = __builtin_amdgcn_mfma_f32_16x16x32_bf16(af, bf1, acc[i][1], 0, 0, 0);
            }
        }
    }

    // epilogue: D row=(lane>>4)*4+r, col=lane&15 (m89-verified)
    const float bb0 = bias[n0 + brow];
    const float bb1 = bias[n0 + brow + 16];
    #pragma unroll
    for (int i = 0; i < 4; ++i) {
        #pragma unroll
        for (int j = 0; j < 2; ++j) {
            const int n = n0 + brow + j * 16;
            const float badd = j ? bb1 : bb0;
            #pragma unroll
            for (int r = 0; r < 4; ++r) {
                const int m = m0 + wr * 64 + i * 16 + (lane >> 4) * 4 + r;
                out[(((long)(m >> 11) * HH + (n >> 6)) * LL + (m & (LL - 1))) * DK + (n & 63)] =
                    acc[i][j][r] + badd;
            }
        }
    }
}

// ---------------- sampled QK^T and M = max - sum/L ----------------
__global__ __launch_bounds__(256) void qk_sample_M(
    const float* __restrict__ q, const float* __restrict__ k,
    const int* __restrict__ idxs, float* __restrict__ M)
{
    const int bh = blockIdx.x >> 5;
    const int l0 = (blockIdx.x & 31) * 64;
    __shared__ float qs[64][DK];
    __shared__ float qk[64][SK];
    const int tid = threadIdx.x;

    const float* qbase = q + ((long)bh * LL + l0) * DK;
    for (int f = tid; f < 64 * DK / 4; f += 256) {
        int row = f >> 4, c4 = (f & 15) * 4;
        *(float4*)&qs[row][c4] = *(const float4*)&qbase[row * DK + c4];
    }
    __syncthreads();

    const float* kbase = k + (long)bh * LL * DK;
    for (int p = tid; p < 64 * SK; p += 256) {
        int lloc = p / SK, s = p - lloc * SK;
        int idx = idxs[(l0 + lloc) * SK + s];
        const float* kr = kbase + (long)idx * DK;
        float acc = 0.f;
        #pragma unroll
        for (int c = 0; c < DK; c += 4) {
            float4 kv = *(const float4*)&kr[c];
            acc += qs[lloc][c] * kv.x + qs[lloc][c + 1] * kv.y
                 + qs[lloc][c + 2] * kv.z + qs[lloc][c + 3] * kv.w;
        }
        qk[lloc][s] = acc;
    }
    __syncthreads();

    if (tid < 64) {
        float mx = -INFINITY, sm = 0.f;
        #pragma unroll
        for (int s = 0; s < SK; ++s) { float t = qk[tid][s]; mx = fmaxf(mx, t); sm += t; }
        M[(long)bh * LL + l0 + tid] = mx - sm / (float)LL;
    }
}

// ---------------- top-40 per (b,h): single wave, in-register ----------------
__global__ __launch_bounds__(64) void topk_M(const float* __restrict__ M, int* __restrict__ Mtop)
{
    const int bh = blockIdx.x;
    const int lane = threadIdx.x;
    float vals[32];
    #pragma unroll
    for (int r = 0; r < 32; ++r) vals[r] = M[(long)bh * LL + r * 64 + lane];

    for (int it = 0; it < UU; ++it) {
        float lm = vals[0];
        #pragma unroll
        for (int r = 1; r < 32; ++r) lm = fmaxf(lm, vals[r]);
        float wm = lm;
        #pragma unroll
        for (int s = 1; s < 64; s <<= 1) wm = fmaxf(wm, __shfl_xor(wm, s, 64));
        unsigned long long mask = __ballot(lm == wm);
        int first = (int)__ffsll(mask) - 1;
        if (lane == first) {
            #pragma unroll
            for (int r = 0; r < 32; ++r) {
                if (vals[r] == wm) { Mtop[bh * UU + it] = r * 64 + lane; vals[r] = -INFINITY; break; }
            }
        }
    }
}

// ---------------- scores for selected queries, written into attns rows ----------------
__global__ __launch_bounds__(256) void scores_topq(
    const float* __restrict__ q, const float* __restrict__ k,
    const int* __restrict__ Mtop, float* __restrict__ attns)
{
    const int bh = blockIdx.x >> 4;
    const int l0 = (blockIdx.x & 15) * 128;
    __shared__ int mt[UU];
    __shared__ float qs[UU][DK];
    const int tid = threadIdx.x;

    if (tid < UU) mt[tid] = Mtop[bh * UU + tid];
    __syncthreads();
    for (int f = tid; f < UU * DK / 4; f += 256) {
        int u = f >> 4, c4 = (f & 15) * 4;
        *(float4*)&qs[u][c4] = *(const float4*)&q[((long)bh * LL + mt[u]) * DK + c4];
    }
    __syncthreads();

    const int tx = tid & 31, ty = tid >> 5;
    const float* kb = k + ((long)bh * LL + l0 + tx * 4) * DK;
    float acc[5][4] = {};
    #pragma unroll
    for (int d0 = 0; d0 < DK; d0 += 4) {
        float4 kv0 = *(const float4*)&kb[0 * DK + d0];
        float4 kv1 = *(const float4*)&kb[1 * DK + d0];
        float4 kv2 = *(const float4*)&kb[2 * DK + d0];
        float4 kv3 = *(const float4*)&kb[3 * DK + d0];
        #pragma unroll
        for (int i = 0; i < 5; ++i) {
            float4 q4 = *(const float4*)&qs[ty + 8 * i][d0];
            acc[i][0] += q4.x * kv0.x + q4.y * kv0.y + q4.z * kv0.z + q4.w * kv0.w;
            acc[i][1] += q4.x * kv1.x + q4.y * kv1.y + q4.z * kv1.z + q4.w * kv1.w;
            acc[i][2] += q4.x * kv2.x + q4.y * kv2.y + q4.z * kv2.z + q4.w * kv2.w;
            acc[i][3] += q4.x * kv3.x + q4.y * kv3.y + q4.z * kv3.z + q4.w * kv3.w;
        }
    }
    const float scale = 0.125f;
    #pragma unroll
    for (int i = 0; i < 5; ++i) {
        int u = ty + 8 * i;
        float4 o4;
        o4.x = acc[i][0] * scale; o4.y = acc[i][1] * scale;
        o4.z = acc[i][2] * scale; o4.w = acc[i][3] * scale;
        *(float4*)&attns[((long)bh * LL + mt[u]) * LL + l0 + tx * 4] = o4;
    }
}

// ---------------- softmax over each selected row (in place in attns) ----------------
__global__ __launch_bounds__(256) void softmax_rows(
    const int* __restrict__ Mtop, float* __restrict__ attns)
{
    const int g = blockIdx.x;            // BH*UU
    const int bh = g / UU;
    const int lsel = Mtop[g];
    float* row = attns + ((long)bh * LL + lsel) * LL;
    const int tid = threadIdx.x;
    const int lane = tid & 63, wave = tid >> 6;
    __shared__ float redm[4];
    __shared__ float reds[4];

    float4 v0 = *(float4*)&row[tid * 4];
    float4 v1 = *(float4*)&row[(tid + 256) * 4];

    float lm = fmaxf(fmaxf(fmaxf(v0.x, v0.y), fmaxf(v0.z, v0.w)),
                     fmaxf(fmaxf(v1.x, v1.y), fmaxf(v1.z, v1.w)));
    #pragma unroll
    for (int s = 32; s > 0; s >>= 1) lm = fmaxf(lm, __shfl_down(lm, s, 64));
    if (lane == 0) redm[wave] = lm;
    __syncthreads();
    const float mx = fmaxf(fmaxf(redm[0], redm[1]), fmaxf(redm[2], redm[3]));

    v0.x = expf(v0.x - mx); v0.y = expf(v0.y - mx);
    v0.z = expf(v0.z - mx); v0.w = expf(v0.w - mx);
    v1.x = expf(v1.x - mx); v1.y = expf(v1.y - mx);
    v1.z = expf(v1.z - mx); v1.w = expf(v1.w - mx);
    float ls = v0.x + v0.y + v0.z + v0.w + v1.x + v1.y + v1.z + v1.w;
    #pragma unroll
    for (int s = 32; s > 0; s >>= 1) ls += __shfl_down(ls, s, 64);
    if (lane == 0) reds[wave] = ls;
    __syncthreads();
    const float inv = 1.0f / (reds[0] + reds[1] + reds[2] + reds[3]);

    v0.x *= inv; v0.y *= inv; v0.z *= inv; v0.w *= inv;
    v1.x *= inv; v1.y *= inv; v1.z *= inv; v1.w *= inv;
    *(float4*)&row[tid * 4] = v0;
    *(float4*)&row[(tid + 256) * 4] = v1;
}

// ---------------- upd partial: per (bh, l-chunk) 40x64 partial GEMM ----------------
__global__ __launch_bounds__(256) void upd_partial(
    const float* __restrict__ v, const int* __restrict__ Mtop,
    const float* __restrict__ attns, float* __restrict__ partial)
{
    const int bh = blockIdx.x >> 4;
    const int ch = blockIdx.x & 15;
    const int l0 = ch * 128;
    __shared__ int mt[UU];
    __shared__ float pl[UU][128];
    __shared__ float vl[128][DK];
    const int tid = threadIdx.x;

    if (tid < UU) mt[tid] = Mtop[bh * UU + tid];
    __syncthreads();
    for (int f = tid; f < UU * 32; f += 256) {
        int u = f >> 5, l4 = (f & 31) * 4;
        *(float4*)&pl[u][l4] = *(const float4*)&attns[((long)bh * LL + mt[u]) * LL + l0 + l4];
    }
    for (int f = tid; f < 128 * 16; f += 256) {
        int l = f >> 4, c4 = (f & 15) * 4;
        *(float4*)&vl[l][c4] = *(const float4*)&v[((long)bh * LL + l0 + l) * DK + c4];
    }
    __syncthreads();

    const int d = tid & 63, uu = tid >> 6;
    float acc[10] = {};
    for (int l = 0; l < 128; ++l) {
        float vv = vl[l][d];
        #pragma unroll
        for (int i = 0; i < 10; ++i) acc[i] += pl[uu * 10 + i][l] * vv;
    }
    #pragma unroll
    for (int i = 0; i < 10; ++i) {
        int u = uu * 10 + i;
        partial[((long)blockIdx.x * UU + u) * DK + d] = acc[i];
    }
}

// ---------------- cumsum of v: 3-phase ----------------
__global__ __launch_bounds__(256) void cumsum_p1(const float* __restrict__ v, float* __restrict__ sums)
{
    const int bh = blockIdx.x;
    const int d = threadIdx.x & 63, sc = threadIdx.x >> 6;
    const int chunk = blockIdx.y * 4 + sc;
    const float* vb = v + ((long)bh * LL + chunk * 32) * DK + d;
    float s = 0.f;
    #pragma unroll
    for (int r = 0; r < 32; ++r) s += vb[r * DK];
    sums[((long)bh * 64 + chunk) * DK + d] = s;
}

__global__ __launch_bounds__(64) void cumsum_p2(float* __restrict__ sums)
{
    const int bh = blockIdx.x, d = threadIdx.x;
    float run = 0.f;
    for (int c = 0; c < 64; ++c) {
        long idx = ((long)bh * 64 + c) * DK + d;
        float t = sums[idx];
        sums[idx] = run;
        run += t;
    }
}

__global__ __launch_bounds__(256) void cumsum_p3(
    const float* __restrict__ v, const float* __restrict__ sums, float* __restrict__ ctx)
{
    const int bh = blockIdx.x;
    const int d = threadIdx.x & 63, sc = threadIdx.x >> 6;
    const int chunk = blockIdx.y * 4 + sc;
    const float* vb = v + ((long)bh * LL + chunk * 32) * DK + d;
    float* cb = ctx + ((long)bh * LL + chunk * 32) * DK + d;
    float run = sums[((long)bh * 64 + chunk) * DK + d];
    #pragma unroll
    for (int r = 0; r < 32; ++r) { run += vb[r * DK]; cb[r * DK] = run; }
}

// ---------------- reduce partials and scatter into ctx ----------------
__global__ __launch_bounds__(64) void reduce_scatter(
    const int* __restrict__ Mtop, const float* __restrict__ partial, float* __restrict__ ctx)
{
    const int g = blockIdx.x;           // BH*UU
    const int bh = g / UU, u = g - bh * UU;
    const int lsel = Mtop[g];
    const int d = threadIdx.x;
    float s = 0.f;
    #pragma unroll
    for (int ch = 0; ch < 16; ++ch)
        s += partial[(((long)(bh * 16 + ch)) * UU + u) * DK + d];
    ctx[((long)bh * LL + lsel) * DK + d] = s;
}

extern "C" void kernel_launch(void* const* d_in, const int* in_sizes, int n_in,
                              void* d_out, int out_size, void* d_ws, size_t ws_size,
                              hipStream_t stream) {
    const float* x  = (const float*)d_in[0];
    const float* Wq = (const float*)d_in[1];
    const float* bq = (const float*)d_in[2];
    const float* Wk = (const float*)d_in[3];
    const float* bk = (const float*)d_in[4];
    const float* Wv = (const float*)d_in[5];
    const float* bv = (const float*)d_in[6];
    const int* idxs = (const int*)d_in[7];

    float* ctx   = (float*)d_out;                            // B*H*L*DK
    float* attns = (float*)d_out + (long)BB * HH * LL * DK;  // B*H*L*L (268 MB)

    char* w = (char*)d_ws;
    float* q       = (float*)w; w += (size_t)BB * HH * LL * DK * 4;
    float* k       = (float*)w; w += (size_t)BB * HH * LL * DK * 4;
    float* v       = (float*)w; w += (size_t)BB * HH * LL * DK * 4;
    float* M       = (float*)w; w += (size_t)BB * HH * LL * 4;
    int*   Mtop    = (int*)w;   w += (size_t)BB * HH * UU * 4;
    float* partial = (float*)w; w += (size_t)BH * 16 * UU * DK * 4;
    float* sums    = (float*)w; w += (size_t)BH * 64 * DK * 4;

    // pack scratch lives in the tail of the attns region (consumed before fill_attns)
    ushort* A2 = (ushort*)(attns + (long)50 * 1024 * 1024);  // 12 MB
    ushort* B2 = (ushort*)(attns + (long)56 * 1024 * 1024);  // 4.5 MB

    // 1) split-bf16 packing
    pack_x<<<1024, 256, 0, stream>>>(x, A2);
    pack_w<<<384, 256, 0, stream>>>(Wq, Wk, Wv, B2);

    // 2) MFMA projection GEMM (q,k,v)
    dim3 g1(4096 / 128, DD / 64, 3);   // 32 x 8 x 3 = 768 blocks
    mfma_proj<<<g1, 256, 0, stream>>>(A2, B2, bq, bk, bv, q, k, v);

    // 3) fill attns with 1/L (after scratch is consumed)
    fill_attns<<<4096, 256, 0, stream>>>(attns, (long)BB * HH * LL * LL / 4);

    // 4) sampled QK^T -> M
    qk_sample_M<<<BH * (LL / 64), 256, 0, stream>>>(q, k, idxs, M);

    // 5) top-40 indices per (b,h)
    topk_M<<<BH, 64, 0, stream>>>(M, Mtop);

    // 6) raw scores into attns rows
    scores_topq<<<BH * 16, 256, 0, stream>>>(q, k, Mtop, attns);

    // 7) softmax in place on the selected rows
    softmax_rows<<<BH * UU, 256, 0, stream>>>(Mtop, attns);

    // 8) upd = attn @ v, split over 16 l-chunks
    upd_partial<<<BH * 16, 256, 0, stream>>>(v, Mtop, attns, partial);

    // 9) context = cumsum(v), 3-phase
    dim3 gc(BH, 16);
    cumsum_p1<<<gc, 256, 0, stream>>>(v, sums);
    cumsum_p2<<<BH, 64, 0, stream>>>(sums);
    cumsum_p3<<<gc, 256, 0, stream>>>(v, sums, ctx);

    // 10) reduce partials, scatter into ctx
    reduce_scatter<<<BH * UU, 64, 0, stream>>>(Mtop, partial, ctx);
}